// Round 1
// baseline (315.154 us; speedup 1.0000x reference)
//
#include <hip/hip_runtime.h>

typedef __attribute__((ext_vector_type(8))) short short8;
typedef __attribute__((ext_vector_type(4))) float floatx4;

#define CIN    192
#define COUTN  192
#define HWDIM  56
#define HWSZ   (56*56)
#define KWT    1728
#define TH     4
#define HALO_Y 6
#define HALO_X 58
#define CK     32
#define NCHUNK 6
#define MT     64

__device__ __forceinline__ short f2bf(float f) {
    union { float f; unsigned u; } v; v.f = f;
    unsigned u = v.u + 0x7FFFu + ((v.u >> 16) & 1u);  // RNE
    return (short)(u >> 16);
}

__global__ __launch_bounds__(256, 2)
void conv3x3_mfma(const float* __restrict__ x, const float* __restrict__ w,
                  const float* __restrict__ bias, float* __restrict__ out) {
    // halo: [y 0..5][x 0..57][c 0..31] bf16, 16B c-groups swizzled by ((x>>1)&3)
    __shared__ __align__(16) short sh_halo[HALO_Y * HALO_X * CK];
    // weights: [off 0..8][m 0..63][c 0..31] bf16, c-groups swizzled by ((m>>1)&3)
    __shared__ __align__(16) short sh_w[9 * MT * CK];

    const int tid  = threadIdx.x;
    const int gh0  = blockIdx.x * TH;   // 14 tiles of 4 rows
    const int o0   = blockIdx.y * MT;   // 3 cout groups of 64
    const int bb   = blockIdx.z;        // batch

    const int lane = tid & 63;
    const int wave = tid >> 6;
    const int wm   = wave >> 1;         // 0..1 : which 32-cout half
    const int wn   = wave & 1;          // 0..1 : which 112-spatial half
    const int g    = lane >> 4;         // quad
    const int col  = lane & 15;

    int ly[7], lx[7];
#pragma unroll
    for (int nt = 0; nt < 7; ++nt) {
        int l = wn * 112 + nt * 16 + col;
        ly[nt] = l / 56;
        lx[nt] = l % 56;
    }

    floatx4 acc[2][7];
#pragma unroll
    for (int mt = 0; mt < 2; ++mt)
#pragma unroll
        for (int nt = 0; nt < 7; ++nt)
            acc[mt][nt] = (floatx4){0.f, 0.f, 0.f, 0.f};

    for (int cc = 0; cc < NCHUNK; ++cc) {
        const int c0 = cc * CK;
        if (cc) __syncthreads();   // protect LDS from overwrite while prior compute reads

        // ---- stage halo: x[bb][c0..c0+32][gh0-1..gh0+4][-1..56] -> bf16 LDS ----
        for (int i = tid; i < 4 * HALO_Y * HALO_X; i += 256) {
            int xx = i % HALO_X;
            int r  = i / HALO_X;
            int y  = r % HALO_Y;
            int cg = r / HALO_Y;                 // 8-channel group 0..3
            int gh = gh0 + y - 1;
            int gw = xx - 1;
            bool ok = ((unsigned)gh < 56u) & ((unsigned)gw < 56u);
            const float* src = x + ((size_t)(bb * CIN + c0 + cg * 8) * HWDIM + gh) * HWDIM + gw;
            short8 v;
#pragma unroll
            for (int k = 0; k < 8; ++k) {
                float f = ok ? src[k * HWSZ] : 0.f;
                v[k] = f2bf(f);
            }
            *(short8*)&sh_halo[(y * HALO_X + xx) * CK + ((cg ^ ((xx >> 1) & 3)) << 3)] = v;
        }

        // ---- stage weights: w[o0+m][(c0+c)*9+off] -> sh_w[off][m][c] ----
        for (int i = tid; i < 9 * MT * 4; i += 256) {
            int cg  = i & 3;
            int off = (i >> 2) % 9;
            int m   = i / 36;
            const float* src = w + (size_t)(o0 + m) * KWT + (c0 + cg * 8) * 9 + off;
            short8 v;
#pragma unroll
            for (int k = 0; k < 8; ++k)
                v[k] = f2bf(src[k * 9]);
            *(short8*)&sh_w[(off * MT + m) * CK + ((cg ^ ((m >> 1) & 3)) << 3)] = v;
        }
        __syncthreads();

        // ---- compute: 9 offsets x (2 m-tiles x 7 n-tiles) MFMAs ----
#pragma unroll
        for (int off = 0; off < 9; ++off) {
            const int di = off / 3, dj = off % 3;
            short8 a[2];
#pragma unroll
            for (int mt = 0; mt < 2; ++mt) {
                int m = wm * 32 + mt * 16 + col;
                a[mt] = *(const short8*)&sh_w[(off * MT + m) * CK + ((g ^ ((m >> 1) & 3)) << 3)];
            }
#pragma unroll
            for (int nt = 0; nt < 7; ++nt) {
                int yy = ly[nt] + di;
                int xp = lx[nt] + dj;
                short8 bfr = *(const short8*)&sh_halo[(yy * HALO_X + xp) * CK + ((g ^ ((xp >> 1) & 3)) << 3)];
                acc[0][nt] = __builtin_amdgcn_mfma_f32_16x16x32_bf16(a[0], bfr, acc[0][nt], 0, 0, 0);
                acc[1][nt] = __builtin_amdgcn_mfma_f32_16x16x32_bf16(a[1], bfr, acc[1][nt], 0, 0, 0);
            }
        }
    }

    // ---- epilogue: D row = g*4 + r, col = lane&15 ----
#pragma unroll
    for (int mt = 0; mt < 2; ++mt) {
        int o = o0 + wm * 32 + mt * 16 + g * 4;
#pragma unroll
        for (int nt = 0; nt < 7; ++nt) {
            int l  = wn * 112 + nt * 16 + col;
            int h  = gh0 + l / 56;
            int ww = l % 56;
            size_t base = ((size_t)(bb * COUTN + o) * HWDIM + h) * HWDIM + ww;
            floatx4 v = acc[mt][nt];
#pragma unroll
            for (int r2 = 0; r2 < 4; ++r2)
                out[base + (size_t)r2 * HWSZ] = v[r2] + bias[o + r2];
        }
    }
}

extern "C" void kernel_launch(void* const* d_in, const int* in_sizes, int n_in,
                              void* d_out, int out_size, void* d_ws, size_t ws_size,
                              hipStream_t stream) {
    const float* x  = (const float*)d_in[0];
    const float* wt = (const float*)d_in[1];
    const float* bi = (const float*)d_in[2];
    float* out = (float*)d_out;
    dim3 grid(14, 3, 32);   // h-tiles, cout-tiles, batch
    conv3x3_mfma<<<grid, dim3(256), 0, stream>>>(x, wt, bi, out);
}

// Round 2
// 205.357 us; speedup vs baseline: 1.5347x; 1.5347x over previous
//
#include <hip/hip_runtime.h>

typedef __attribute__((ext_vector_type(8))) short short8;
typedef __attribute__((ext_vector_type(4))) float floatx4;

#define CIN    192
#define COUTN  192
#define HWDIM  56
#define HWSZ   (56*56)
#define KWT    1728
#define TH     4
#define HY     6
#define PH     58
#define CK     32
#define NCHUNK 6
#define MT     64

// ws layout: xpack [b 32][cc 6][h' 58][x' 58][c 32] bf16 ; wpack [og 3][cc 6][off 9][m 64][c 32] bf16
#define XPACK_SHORTS (32u*6u*58u*58u*32u)   /* 20,668,416 shorts = 41,336,832 B */
#define WPACK_SHORTS (3u*6u*9u*64u*32u)     /* 331,776 shorts = 663,552 B */
#define WS_NEEDED    ((size_t)(XPACK_SHORTS + WPACK_SHORTS) * 2u)

__device__ __forceinline__ short f2bf(float f) {
    union { float f; unsigned u; } v; v.f = f;
    unsigned u = v.u + 0x7FFFu + ((v.u >> 16) & 1u);  // RNE
    return (short)(u >> 16);
}

// ---------------- pre-pass: pack x to padded NHWC-chunked bf16 ----------------
__global__ __launch_bounds__(256)
void pack_x(const float* __restrict__ x, short* __restrict__ xp) {
    int idx = blockIdx.x * 256 + threadIdx.x;          // one thread per 16B chunk
    const int TOT = 32 * 6 * 58 * 58 * 4;
    if (idx >= TOT) return;
    int cg  = idx & 3;
    int pix = idx >> 2;
    int xq  = pix % 58;
    int t   = pix / 58;
    int hq  = t % 58;
    int bc  = t / 58;                                   // b*6+cc
    int cc  = bc % 6;
    int b   = bc / 6;
    short8 v;
    if (hq == 0 || hq == 57 || xq == 0 || xq == 57) {
        v = (short8){0, 0, 0, 0, 0, 0, 0, 0};
    } else {
        const float* src = x + ((size_t)(b * CIN + cc * 32 + cg * 8) * HWDIM + (hq - 1)) * HWDIM + (xq - 1);
#pragma unroll
        for (int k = 0; k < 8; ++k) v[k] = f2bf(src[(size_t)k * HWSZ]);
    }
    *(short8*)(xp + (size_t)idx * 8) = v;
}

// ---------------- pre-pass: pack weights to [og][cc][off][m][c] bf16 ----------------
__global__ __launch_bounds__(256)
void pack_w(const float* __restrict__ w, short* __restrict__ wp) {
    int idx = blockIdx.x * 256 + threadIdx.x;          // one thread per 16B chunk
    const int TOT = 3 * 6 * 9 * 64 * 4;
    if (idx >= TOT) return;
    int cg = idx & 3;
    int m  = (idx >> 2) & 63;
    int t  = idx >> 8;                                  // og*54 + cc*9 + off
    int off = t % 9;  t /= 9;
    int cc  = t % 6;
    int og  = t / 6;
    short8 v;
#pragma unroll
    for (int k = 0; k < 8; ++k)
        v[k] = f2bf(w[(size_t)(og * 64 + m) * KWT + (cc * 32 + cg * 8 + k) * 9 + off]);
    *(short8*)(wp + (size_t)idx * 8) = v;
}

// ---------------- main: implicit-GEMM conv, halo via global_load_lds ----------------
__global__ __launch_bounds__(256, 2)
void conv_main(const short* __restrict__ xp, const short* __restrict__ wp,
               const float* __restrict__ bias, float* __restrict__ out) {
    __shared__ __align__(16) short sh[HY * PH * CK];    // 22,272 B

    const int tid  = threadIdx.x;
    const int gh0  = blockIdx.x * TH;
    const int og   = blockIdx.y;
    const int bb   = blockIdx.z;
    const int lane = tid & 63;
    const int wave = tid >> 6;
    const int wm   = wave >> 1;
    const int wn   = wave & 1;
    const int g    = lane >> 4;
    const int col  = lane & 15;

    int ly[7], lx[7];
#pragma unroll
    for (int nt = 0; nt < 7; ++nt) {
        int l = wn * 112 + nt * 16 + col;
        ly[nt] = l / 56;
        lx[nt] = l % 56;
    }

    floatx4 acc[2][7];
#pragma unroll
    for (int mt = 0; mt < 2; ++mt)
#pragma unroll
        for (int nt = 0; nt < 7; ++nt)
            acc[mt][nt] = (floatx4){0.f, 0.f, 0.f, 0.f};

    const short8* wpk = (const short8*)wp;
    const int wlbase = wave * 64;                       // wave-uniform lds chunk base

    for (int cc = 0; cc < NCHUNK; ++cc) {
        if (cc) __syncthreads();                        // all waves done reading prev tile

        // stage halo: one contiguous 22,272 B region, lane-linear -> global_load_lds x16B
        const short* src = xp + ((size_t)(bb * 6 + cc) * (PH * PH) + (size_t)gh0 * PH) * CK;
#pragma unroll
        for (int j = 0; j < 6; ++j) {
            int idx = j * 256 + tid;
            if (idx < HY * PH * 4) {                    // 1392 chunks
                __builtin_amdgcn_global_load_lds(
                    (const __attribute__((address_space(1))) void*)(src + (size_t)idx * 8),
                    (__attribute__((address_space(3))) void*)(sh + (j * 256 + wlbase) * 8),
                    16, 0, 0);
            }
        }

        // a-frags to registers (coalesced L2-hit dwordx4); drained by the barrier's vmcnt(0)
        short8 afr[9][2];
#pragma unroll
        for (int off = 0; off < 9; ++off)
#pragma unroll
            for (int mt = 0; mt < 2; ++mt)
                afr[off][mt] = wpk[((og * 6 + cc) * 9 + off) * 256 + (wm * 32 + mt * 16 + col) * 4 + g];

        __syncthreads();

#pragma unroll
        for (int off = 0; off < 9; ++off) {
            const int di = off / 3, dj = off % 3;
#pragma unroll
            for (int nt = 0; nt < 7; ++nt) {
                short8 bfr = *(const short8*)&sh[((ly[nt] + di) * PH + lx[nt] + dj) * CK + g * 8];
                acc[0][nt] = __builtin_amdgcn_mfma_f32_16x16x32_bf16(afr[off][0], bfr, acc[0][nt], 0, 0, 0);
                acc[1][nt] = __builtin_amdgcn_mfma_f32_16x16x32_bf16(afr[off][1], bfr, acc[1][nt], 0, 0, 0);
            }
        }
    }

    // epilogue: D row = g*4 + r, col = lane&15
#pragma unroll
    for (int mt = 0; mt < 2; ++mt) {
        int o = og * 64 + wm * 32 + mt * 16 + g * 4;
#pragma unroll
        for (int nt = 0; nt < 7; ++nt) {
            int l  = wn * 112 + nt * 16 + col;
            int h  = gh0 + l / 56;
            int ww = l % 56;
            size_t base = ((size_t)(bb * COUTN + o) * HWDIM + h) * HWDIM + ww;
            floatx4 v = acc[mt][nt];
#pragma unroll
            for (int r2 = 0; r2 < 4; ++r2)
                out[base + (size_t)r2 * HWSZ] = v[r2] + bias[o + r2];
        }
    }
}

// ---------------- fallback (round-1 kernel) if ws too small ----------------
__global__ __launch_bounds__(256, 2)
void conv3x3_fb(const float* __restrict__ x, const float* __restrict__ w,
                const float* __restrict__ bias, float* __restrict__ out) {
    __shared__ __align__(16) short sh_halo[HY * PH * CK];
    __shared__ __align__(16) short sh_w[9 * MT * CK];
    const int tid = threadIdx.x;
    const int gh0 = blockIdx.x * TH;
    const int o0  = blockIdx.y * MT;
    const int bb  = blockIdx.z;
    const int lane = tid & 63, wave = tid >> 6;
    const int wm = wave >> 1, wn = wave & 1;
    const int g = lane >> 4, col = lane & 15;
    int ly[7], lx[7];
#pragma unroll
    for (int nt = 0; nt < 7; ++nt) {
        int l = wn * 112 + nt * 16 + col;
        ly[nt] = l / 56; lx[nt] = l % 56;
    }
    floatx4 acc[2][7];
#pragma unroll
    for (int mt = 0; mt < 2; ++mt)
#pragma unroll
        for (int nt = 0; nt < 7; ++nt) acc[mt][nt] = (floatx4){0.f,0.f,0.f,0.f};
    for (int cc = 0; cc < NCHUNK; ++cc) {
        const int c0 = cc * CK;
        if (cc) __syncthreads();
        for (int i = tid; i < 4 * HY * PH; i += 256) {
            int xx = i % PH, r = i / PH, y = r % HY, cg = r / HY;
            int gh = gh0 + y - 1, gw = xx - 1;
            bool ok = ((unsigned)gh < 56u) & ((unsigned)gw < 56u);
            const float* src = x + ((size_t)(bb * CIN + c0 + cg * 8) * HWDIM + gh) * HWDIM + gw;
            short8 v;
#pragma unroll
            for (int k = 0; k < 8; ++k) v[k] = f2bf(ok ? src[k * HWSZ] : 0.f);
            *(short8*)&sh_halo[(y * PH + xx) * CK + ((cg ^ ((xx >> 1) & 3)) << 3)] = v;
        }
        for (int i = tid; i < 9 * MT * 4; i += 256) {
            int cg = i & 3, off = (i >> 2) % 9, m = i / 36;
            const float* src = w + (size_t)(o0 + m) * KWT + (c0 + cg * 8) * 9 + off;
            short8 v;
#pragma unroll
            for (int k = 0; k < 8; ++k) v[k] = f2bf(src[k * 9]);
            *(short8*)&sh_w[(off * MT + m) * CK + ((cg ^ ((m >> 1) & 3)) << 3)] = v;
        }
        __syncthreads();
#pragma unroll
        for (int off = 0; off < 9; ++off) {
            const int di = off / 3, dj = off % 3;
            short8 a[2];
#pragma unroll
            for (int mt = 0; mt < 2; ++mt) {
                int m = wm * 32 + mt * 16 + col;
                a[mt] = *(const short8*)&sh_w[(off * MT + m) * CK + ((g ^ ((m >> 1) & 3)) << 3)];
            }
#pragma unroll
            for (int nt = 0; nt < 7; ++nt) {
                int yy = ly[nt] + di, xpp = lx[nt] + dj;
                short8 bfr = *(const short8*)&sh_halo[(yy * PH + xpp) * CK + ((g ^ ((xpp >> 1) & 3)) << 3)];
                acc[0][nt] = __builtin_amdgcn_mfma_f32_16x16x32_bf16(a[0], bfr, acc[0][nt], 0, 0, 0);
                acc[1][nt] = __builtin_amdgcn_mfma_f32_16x16x32_bf16(a[1], bfr, acc[1][nt], 0, 0, 0);
            }
        }
    }
#pragma unroll
    for (int mt = 0; mt < 2; ++mt) {
        int o = o0 + wm * 32 + mt * 16 + g * 4;
#pragma unroll
        for (int nt = 0; nt < 7; ++nt) {
            int l = wn * 112 + nt * 16 + col;
            int h = gh0 + l / 56, ww = l % 56;
            size_t base = ((size_t)(bb * COUTN + o) * HWDIM + h) * HWDIM + ww;
            floatx4 v = acc[mt][nt];
#pragma unroll
            for (int r2 = 0; r2 < 4; ++r2)
                out[base + (size_t)r2 * HWSZ] = v[r2] + bias[o + r2];
        }
    }
}

extern "C" void kernel_launch(void* const* d_in, const int* in_sizes, int n_in,
                              void* d_out, int out_size, void* d_ws, size_t ws_size,
                              hipStream_t stream) {
    const float* x  = (const float*)d_in[0];
    const float* wt = (const float*)d_in[1];
    const float* bi = (const float*)d_in[2];
    float* out = (float*)d_out;

    if (ws_size >= WS_NEEDED) {
        short* xpk = (short*)d_ws;
        short* wpk = xpk + XPACK_SHORTS;
        {
            int tot = 32 * 6 * 58 * 58 * 4;
            pack_x<<<(tot + 255) / 256, 256, 0, stream>>>(x, xpk);
        }
        {
            int tot = 3 * 6 * 9 * 64 * 4;
            pack_w<<<(tot + 255) / 256, 256, 0, stream>>>(wt, wpk);
        }
        conv_main<<<dim3(14, 3, 32), dim3(256), 0, stream>>>(xpk, wpk, bi, out);
    } else {
        conv3x3_fb<<<dim3(14, 3, 32), dim3(256), 0, stream>>>(x, wt, bi, out);
    }
}